// Round 1
// baseline (251.682 us; speedup 1.0000x reference)
//
#include <hip/hip_runtime.h>

// Problem constants (from reference)
constexpr int BATCH = 16384;
constexpr int NN    = 4096;   // NUM_NEURONS
constexpr int BS    = 32;     // BLOCK_SIZE
constexpr int NB    = NN / BS; // 128 blocks

constexpr int THREADS        = 256;
constexpr int ROWS_PER_THREAD = 2;
constexpr int ROWS_PER_WG    = THREADS * ROWS_PER_THREAD; // 512

// out[b, n*32+l] = relu( sum_k v[b,n*32+k]*A[n,k,l] + dx[b,0]*B[n*32+l,0] + dx[b,1]*B[n*32+l,1] + bias )
__global__ __launch_bounds__(THREADS) void tn_kernel(
    const float* __restrict__ v,
    const float* __restrict__ dx,
    const float* __restrict__ A,
    const float* __restrict__ Bm,
    const float* __restrict__ bsc,
    float* __restrict__ out)
{
    __shared__ float4 Alds[BS * BS / 4];  // 256 x float4 : A[k][l], l fastest
    __shared__ float  Blds[BS * 2];       // B rows for this block's 32 output cols

    const int tid  = threadIdx.x;
    const int nblk = blockIdx.x & (NB - 1);   // neuron block
    const int rt   = blockIdx.x >> 7;         // row tile

    // Stage A[nblk] (4 KB) : 256 threads x one float4 each
    Alds[tid] = reinterpret_cast<const float4*>(A + nblk * (BS * BS))[tid];
    if (tid < 16)
        reinterpret_cast<float4*>(Blds)[tid] =
            reinterpret_cast<const float4*>(Bm + nblk * (BS * 2))[tid];
    __syncthreads();

    const float bias = *bsc;

    const int row0 = rt * ROWS_PER_WG + tid;
    const int row1 = row0 + THREADS;

    const float4* vr0 = reinterpret_cast<const float4*>(v + (size_t)row0 * NN + nblk * BS);
    const float4* vr1 = reinterpret_cast<const float4*>(v + (size_t)row1 * NN + nblk * BS);

    // Preload both 128B row slices (16 outstanding dwordx4 loads)
    float4 w0[8], w1[8];
#pragma unroll
    for (int i = 0; i < 8; ++i) w0[i] = vr0[i];
#pragma unroll
    for (int i = 0; i < 8; ++i) w1[i] = vr1[i];

    const float2 d0 = reinterpret_cast<const float2*>(dx)[row0];
    const float2 d1 = reinterpret_cast<const float2*>(dx)[row1];

    float acc0[BS], acc1[BS];
#pragma unroll
    for (int l = 0; l < BS; ++l) { acc0[l] = 0.0f; acc1[l] = 0.0f; }

    // 32x32 block matmul; A from LDS via wave-uniform broadcast (k,l4 loop consts)
#pragma unroll
    for (int k = 0; k < BS; ++k) {
        const float vk0 = reinterpret_cast<const float*>(w0)[k];  // constant idx after unroll
        const float vk1 = reinterpret_cast<const float*>(w1)[k];
#pragma unroll
        for (int l4 = 0; l4 < 8; ++l4) {
            const float4 a = Alds[k * 8 + l4];
            acc0[l4*4+0] = fmaf(vk0, a.x, acc0[l4*4+0]);
            acc0[l4*4+1] = fmaf(vk0, a.y, acc0[l4*4+1]);
            acc0[l4*4+2] = fmaf(vk0, a.z, acc0[l4*4+2]);
            acc0[l4*4+3] = fmaf(vk0, a.w, acc0[l4*4+3]);
            acc1[l4*4+0] = fmaf(vk1, a.x, acc1[l4*4+0]);
            acc1[l4*4+1] = fmaf(vk1, a.y, acc1[l4*4+1]);
            acc1[l4*4+2] = fmaf(vk1, a.z, acc1[l4*4+2]);
            acc1[l4*4+3] = fmaf(vk1, a.w, acc1[l4*4+3]);
        }
    }

    // Epilogue: + dx @ B^T + bias, ReLU, vectorized store
    float4* o0 = reinterpret_cast<float4*>(out + (size_t)row0 * NN + nblk * BS);
    float4* o1 = reinterpret_cast<float4*>(out + (size_t)row1 * NN + nblk * BS);
#pragma unroll
    for (int l4 = 0; l4 < 8; ++l4) {
        float e0[4], e1[4];
#pragma unroll
        for (int j = 0; j < 4; ++j) {
            const int l = l4 * 4 + j;
            const float b0 = Blds[2*l], b1 = Blds[2*l+1];
            float lin0 = fmaf(d0.x, b0, fmaf(d0.y, b1, acc0[l] + bias));
            float lin1 = fmaf(d1.x, b0, fmaf(d1.y, b1, acc1[l] + bias));
            e0[j] = fmaxf(lin0, 0.0f);
            e1[j] = fmaxf(lin1, 0.0f);
        }
        o0[l4] = make_float4(e0[0], e0[1], e0[2], e0[3]);
        o1[l4] = make_float4(e1[0], e1[1], e1[2], e1[3]);
    }
}

extern "C" void kernel_launch(void* const* d_in, const int* in_sizes, int n_in,
                              void* d_out, int out_size, void* d_ws, size_t ws_size,
                              hipStream_t stream) {
    const float* v  = (const float*)d_in[0];  // [16384,4096]
    const float* dx = (const float*)d_in[1];  // [16384,2]
    const float* A  = (const float*)d_in[2];  // [128,32,32]
    const float* Bm = (const float*)d_in[3];  // [4096,2]
    const float* b  = (const float*)d_in[4];  // scalar
    float* out = (float*)d_out;               // [16384,4096]

    const int grid = NB * (BATCH / ROWS_PER_WG); // 128 * 32 = 4096
    tn_kernel<<<dim3(grid), dim3(THREADS), 0, stream>>>(v, dx, A, Bm, b, out);
}

// Round 3
// 115.139 us; speedup vs baseline: 2.1859x; 2.1859x over previous
//
#include <hip/hip_runtime.h>

// Problem constants (from reference)
constexpr int BATCH = 16384;
constexpr int NN    = 4096;    // NUM_NEURONS
constexpr int BS    = 32;      // BLOCK_SIZE
constexpr int NB    = NN / BS; // 128 blocks

constexpr int THREADS     = 256;           // 4 waves
constexpr int ROWS_PER_WG = 512;
constexpr int ROWS_PER_IT = 32;            // 4 waves x 8 rows
constexpr int ITERS       = ROWS_PER_WG / ROWS_PER_IT; // 16

typedef float f32x4 __attribute__((ext_vector_type(4)));
typedef float f32x2 __attribute__((ext_vector_type(2)));

// Lane layout within a wave: r = lane>>3 (row in 8-row slab), g = lane&7
// (column float4-quad). Each dwordx4 global access covers 8 full 128-B lines.
//
// Per k-step: broadcast v[row,k] from lane (r, k>>2) component (k&3) via
// ds_swizzle (BitMode: and=0x18 keeps row bits, or=(k>>2) selects source lane
// within each 8-lane group), read A[k][4g..4g+3] from LDS (banks 4g+e span
// all 32, broadcast over r -> conflict-free), 4 FMAs into acc.
template <int K>
struct KStep {
    static __device__ __forceinline__ void run(const f32x4 w,
                                               const f32x4* __restrict__ Alds,
                                               int g, float* __restrict__ acc) {
        constexpr int s = K >> 2;   // source lane within 8-lane group
        constexpr int e = K & 3;    // component of that lane's float4
        const float we = w[e];
        const float vk = __int_as_float(
            __builtin_amdgcn_ds_swizzle(__float_as_int(we), (s << 5) | 0x18));
        const f32x4 a = Alds[K * 8 + g];
        acc[0] = fmaf(vk, a.x, acc[0]);
        acc[1] = fmaf(vk, a.y, acc[1]);
        acc[2] = fmaf(vk, a.z, acc[2]);
        acc[3] = fmaf(vk, a.w, acc[3]);
        KStep<K + 1>::run(w, Alds, g, acc);
    }
};
template <>
struct KStep<BS> {
    static __device__ __forceinline__ void run(const f32x4,
                                               const f32x4* __restrict__,
                                               int, float* __restrict__) {}
};

__global__ __launch_bounds__(THREADS) void tn_kernel(
    const float* __restrict__ v,
    const float* __restrict__ dx,
    const float* __restrict__ A,
    const float* __restrict__ Bm,
    const float* __restrict__ bsc,
    float* __restrict__ out)
{
    __shared__ f32x4 Alds[BS * BS / 4]; // A[k][l], l fastest (256 x float4)

    const int tid  = threadIdx.x;
    const int nblk = blockIdx.x & (NB - 1);
    const int rt   = blockIdx.x >> 7;

    // Stage A[nblk] (4 KB): 256 threads x one float4
    Alds[tid] = reinterpret_cast<const f32x4*>(A + nblk * (BS * BS))[tid];
    __syncthreads();

    const float bias = *bsc;
    const int lane = tid & 63;
    const int wv   = tid >> 6;
    const int r    = lane >> 3;
    const int g    = lane & 7;

    // B rows for this lane's 4 output columns: Bm[nblk*32+4g+j][0..1], j=0..3
    // = 8 contiguous floats; L2-resident (B is 32 KB total).
    const f32x4* Bp = reinterpret_cast<const f32x4*>(Bm + nblk * (BS * 2) + g * 8);
    const f32x4 B0 = Bp[0];  // {B[c0][0],B[c0][1],B[c1][0],B[c1][1]}
    const f32x4 B1 = Bp[1];  // {B[c2][0],B[c2][1],B[c3][0],B[c3][1]}

    int row = rt * ROWS_PER_WG + wv * 8 + r;
    size_t off = (size_t)row * NN + nblk * BS + g * 4;

    // Software pipeline: prefetch next slab's v/dx while computing current.
    f32x4 w  = __builtin_nontemporal_load(reinterpret_cast<const f32x4*>(v + off));
    f32x2 dd = *reinterpret_cast<const f32x2*>(dx + (size_t)row * 2);

#pragma unroll 1
    for (int it = 0; it < ITERS; ++it) {
        f32x4 wn  = w;
        f32x2 ddn = dd;
        if (it < ITERS - 1) {
            wn  = __builtin_nontemporal_load(
                      reinterpret_cast<const f32x4*>(v + off + (size_t)ROWS_PER_IT * NN));
            ddn = *reinterpret_cast<const f32x2*>(dx + (size_t)(row + ROWS_PER_IT) * 2);
        }

        float acc[4] = {0.f, 0.f, 0.f, 0.f};
        KStep<0>::run(w, Alds, g, acc);

        f32x4 o;
        o.x = fmaxf(fmaf(dd.x, B0.x, fmaf(dd.y, B0.y, acc[0] + bias)), 0.f);
        o.y = fmaxf(fmaf(dd.x, B0.z, fmaf(dd.y, B0.w, acc[1] + bias)), 0.f);
        o.z = fmaxf(fmaf(dd.x, B1.x, fmaf(dd.y, B1.y, acc[2] + bias)), 0.f);
        o.w = fmaxf(fmaf(dd.x, B1.z, fmaf(dd.y, B1.w, acc[3] + bias)), 0.f);
        __builtin_nontemporal_store(o, reinterpret_cast<f32x4*>(out + off));

        w = wn; dd = ddn;
        row += ROWS_PER_IT;
        off += (size_t)ROWS_PER_IT * NN;
    }
}

extern "C" void kernel_launch(void* const* d_in, const int* in_sizes, int n_in,
                              void* d_out, int out_size, void* d_ws, size_t ws_size,
                              hipStream_t stream) {
    const float* v  = (const float*)d_in[0];  // [16384,4096]
    const float* dx = (const float*)d_in[1];  // [16384,2]
    const float* A  = (const float*)d_in[2];  // [128,32,32]
    const float* Bm = (const float*)d_in[3];  // [4096,2]
    const float* b  = (const float*)d_in[4];  // scalar
    float* out = (float*)d_out;               // [16384,4096]

    const int grid = NB * (BATCH / ROWS_PER_WG); // 128 * 32 = 4096
    tn_kernel<<<dim3(grid), dim3(THREADS), 0, stream>>>(v, dx, A, Bm, b, out);
}